// Round 2
// baseline (1173.083 us; speedup 1.0000x reference)
//
#include <hip/hip_runtime.h>

typedef __attribute__((ext_vector_type(8))) short short8;
typedef __attribute__((ext_vector_type(4))) float f32x4;

#define DI static __device__ __forceinline__

DI unsigned short f2bf(float f) {
  unsigned u = __builtin_bit_cast(unsigned, f);
  u += 0x7fffu + ((u >> 16) & 1u);
  return (unsigned short)(u >> 16);
}
DI float bf2f(unsigned short b) {
  unsigned u = ((unsigned)b) << 16;
  return __builtin_bit_cast(float, u);
}

static constexpr int NT   = 2048;   // B*S tokens
static constexpr int SEQ  = 1024;
static constexpr int DIM  = 1024;
static constexpr int NH   = 16;
static constexpr int NKV  = 8;
static constexpr int HD   = 64;
static constexpr int KVD  = NKV * HD;  // 512
static constexpr int MDIM = 3584;
static constexpr int NE   = 8;

// ---------------------------------------------------------------- rmsnorm
__global__ void __launch_bounds__(256) rmsnorm_kernel(const float* __restrict__ x,
                                                      const float* __restrict__ w,
                                                      unsigned short* __restrict__ out) {
  int row = blockIdx.x;
  const float* xr = x + (size_t)row * DIM;
  int i = threadIdx.x * 4;
  float4 v = *(const float4*)(xr + i);
  float s = v.x * v.x + v.y * v.y + v.z * v.z + v.w * v.w;
  for (int o = 32; o; o >>= 1) s += __shfl_xor(s, o);
  __shared__ float red[4];
  if ((threadIdx.x & 63) == 0) red[threadIdx.x >> 6] = s;
  __syncthreads();
  s = red[0] + red[1] + red[2] + red[3];
  float r = rsqrtf(s * (1.0f / DIM) + 1e-6f);
  float4 wv = *(const float4*)(w + i);
  ushort4 o4;
  o4.x = f2bf(v.x * r * wv.x);
  o4.y = f2bf(v.y * r * wv.y);
  o4.z = f2bf(v.z * r * wv.z);
  o4.w = f2bf(v.w * r * wv.w);
  *(ushort4*)(out + (size_t)row * DIM + i) = o4;
}

// ---------------------------------------------------------------- generic GEMM
// A: bf16 [M x K] row-major (rows optionally gathered), B: fp32 [K x N] row-major
// (converted to bf16 in staging). Block: 256 thr / 4 waves, tile 64x64, BK=32.
// ROW_MODE: 0 = none; 2 = A row & C row = lists[] value (per-expert, B offset by e).
// EPI: 0 = bf16 C; 1 = fp32 C = acc + resid; 2 = fp32 C = acc.
template <int ROW_MODE, int EPI>
__global__ void __launch_bounds__(256) gemm_kernel(
    const unsigned short* __restrict__ A, int lda,
    const float* __restrict__ B, int ldb, size_t b_estride,
    void* __restrict__ Cv, int ldc,
    const float* __restrict__ resid,
    int M, int K,
    const int* __restrict__ lists, const int* __restrict__ cnt) {
  int e = blockIdx.z;
  int count = M;
  const int* lst = nullptr;
  const float* Bp = B;
  if (ROW_MODE != 0) {
    count = cnt[e];
    if (count <= 0) return;
    lst = lists + e * NT;
    Bp = B + b_estride * (size_t)e;
  }
  int m0 = blockIdx.y * 64;
  if (m0 >= count) return;
  int n0 = blockIdx.x * 64;

  __shared__ unsigned short As[64][40];
  __shared__ unsigned short Bs[64][40];

  int tid = threadIdx.x, wave = tid >> 6, lane = tid & 63;
  f32x4 acc[4] = {};

  int sr = tid >> 2, skc = (tid & 3) * 8;
  int arow;
  {
    int mrow = m0 + sr;
    if (ROW_MODE == 0) arow = mrow;
    else arow = lst[mrow < count ? mrow : count - 1];
  }
  const unsigned short* Aptr = A + (size_t)arow * lda + skc;
  int snc = (tid & 15) * 4, skr = tid >> 4;

  for (int k0 = 0; k0 < K; k0 += 32) {
    __syncthreads();
    *(uint4*)&As[sr][skc] = *(const uint4*)(Aptr + k0);
#pragma unroll
    for (int p = 0; p < 2; ++p) {
      int kr = skr + p * 16;
      const float* src = Bp + (size_t)(k0 + kr) * ldb + n0 + snc;
      float4 v = *(const float4*)src;
      Bs[snc + 0][kr] = f2bf(v.x);
      Bs[snc + 1][kr] = f2bf(v.y);
      Bs[snc + 2][kr] = f2bf(v.z);
      Bs[snc + 3][kr] = f2bf(v.w);
    }
    __syncthreads();
    short8 a = *(const short8*)&As[wave * 16 + (lane & 15)][(lane >> 4) * 8];
#pragma unroll
    for (int cb = 0; cb < 4; ++cb) {
      short8 b = *(const short8*)&Bs[cb * 16 + (lane & 15)][(lane >> 4) * 8];
      acc[cb] = __builtin_amdgcn_mfma_f32_16x16x32_bf16(a, b, acc[cb], 0, 0, 0);
    }
  }

  int col = lane & 15, rbase = wave * 16 + ((lane >> 4) << 2);
#pragma unroll
  for (int r = 0; r < 4; ++r) {
    int mrow = m0 + rbase + r;
    if (ROW_MODE != 0 && mrow >= count) continue;
    size_t crow = (ROW_MODE == 0) ? (size_t)mrow : (size_t)lst[mrow];
#pragma unroll
    for (int cb = 0; cb < 4; ++cb) {
      int n = n0 + cb * 16 + col;
      float val = acc[cb][r];
      if (EPI == 0)
        ((unsigned short*)Cv)[crow * ldc + n] = f2bf(val);
      else if (EPI == 1)
        ((float*)Cv)[crow * ldc + n] = val + resid[crow * ldc + n];
      else
        ((float*)Cv)[crow * ldc + n] = val;
    }
  }
}

// ---------------------------------------------------------------- RoPE (in-place, bf16 q/k)
__global__ void __launch_bounds__(256) rope_kernel(unsigned short* __restrict__ qb,
                                                   unsigned short* __restrict__ kb) {
  int g = blockIdx.x * 256 + threadIdx.x;
  int i = g & 31;
  int hh = (g >> 5) % (NH + NKV);
  int tok = g / (32 * (NH + NKV));
  if (tok >= NT) return;
  int s = tok & (SEQ - 1);
  // inv_freq = 10000^(-i/32); log2(10000)=13.287712379549449
  float inv = exp2f((float)i * (-13.287712379549449f / 32.0f));
  float ang = (float)s * inv;
  float sn = sinf(ang);
  float c  = cosf(ang);
  unsigned short* ptr = (hh < NH) ? (qb + (size_t)tok * DIM + hh * HD)
                                  : (kb + (size_t)tok * KVD + (hh - NH) * HD);
  float a = bf2f(ptr[i]), b2 = bf2f(ptr[i + 32]);
  ptr[i]      = f2bf(a * c - b2 * sn);
  ptr[i + 32] = f2bf(b2 * c + a * sn);
}

// ---------------------------------------------------------------- attention
// 1 wave per (b, head, 16-row q tile). Scores in 64KB LDS (fp32), column
// XOR-swizzle ((r&3)<<3) to break the row-stride-1024 bank conflict on the
// P-fragment re-read.
__global__ void __launch_bounds__(64) attn_kernel(const unsigned short* __restrict__ qb,
                                                  const unsigned short* __restrict__ kb,
                                                  const unsigned short* __restrict__ vb,
                                                  unsigned short* __restrict__ ao) {
  __shared__ float sc[16][1024];
  int bid = blockIdx.x;
  int qt = bid & 63;
  int h = (bid >> 6) & 15;
  int b = bid >> 10;
  int lane = threadIdx.x;
  int l15 = lane & 15, lhi = lane >> 4;
  int qrow0 = qt * 16;
  int kvh = h >> 1;

  const unsigned short* qp = qb + ((size_t)(b * SEQ + qrow0 + l15)) * DIM + h * HD + lhi * 8;
  short8 aq0 = *(const short8*)qp;
  short8 aq1 = *(const short8*)(qp + 32);

  int nkt = qt + 1;
  for (int kt = 0; kt < nkt; ++kt) {
    const unsigned short* kp = kb + ((size_t)(b * SEQ + kt * 16 + l15)) * KVD + kvh * HD + lhi * 8;
    short8 bk0 = *(const short8*)kp;
    short8 bk1 = *(const short8*)(kp + 32);
    f32x4 acc = {};
    acc = __builtin_amdgcn_mfma_f32_16x16x32_bf16(aq0, bk0, acc, 0, 0, 0);
    acc = __builtin_amdgcn_mfma_f32_16x16x32_bf16(aq1, bk1, acc, 0, 0, 0);
#pragma unroll
    for (int r = 0; r < 4; ++r) {
      int qr = lhi * 4 + r;
      int kpos = kt * 16 + l15;
      float v = acc[r] * 0.125f;
      if (kpos > qrow0 + qr) v = -1e30f;
      sc[qr][kpos ^ ((qr & 3) << 3)] = v;
    }
  }
  int kvalid = nkt * 16;
  int kpad = (kvalid + 31) & ~31;
  if (kvalid < kpad && lane < 16) {
#pragma unroll
    for (int r = 0; r < 16; ++r) sc[r][(kvalid + lane) ^ ((r & 3) << 3)] = -1e30f;
  }
  __syncthreads();

  for (int r = 0; r < 16; ++r) {
    int sw = (r & 3) << 3;
    float m = -1e30f;
    for (int k = lane; k < kpad; k += 64) m = fmaxf(m, sc[r][k ^ sw]);
    for (int o = 32; o; o >>= 1) m = fmaxf(m, __shfl_xor(m, o));
    float sum = 0.f;
    for (int k = lane; k < kpad; k += 64) {
      float p = __expf(sc[r][k ^ sw] - m);
      sc[r][k ^ sw] = p;
      sum += p;
    }
    for (int o = 32; o; o >>= 1) sum += __shfl_xor(sum, o);
    float inv = 1.f / sum;
    for (int k = lane; k < kpad; k += 64) sc[r][k ^ sw] *= inv;
  }
  __syncthreads();

  int nks = kpad >> 5;
  int psw = (l15 & 3) << 3;
  for (int cb = 0; cb < 4; ++cb) {
    f32x4 acc = {};
    for (int ks = 0; ks < nks; ++ks) {
      int kk = ks * 32 + lhi * 8;
      const float* pp = &sc[l15][kk ^ psw];
      float4 p0 = *(const float4*)pp;
      float4 p1 = *(const float4*)(pp + 4);
      short8 pa;
      pa[0] = (short)f2bf(p0.x); pa[1] = (short)f2bf(p0.y);
      pa[2] = (short)f2bf(p0.z); pa[3] = (short)f2bf(p0.w);
      pa[4] = (short)f2bf(p1.x); pa[5] = (short)f2bf(p1.y);
      pa[6] = (short)f2bf(p1.z); pa[7] = (short)f2bf(p1.w);
      const unsigned short* vp = vb + ((size_t)(b * SEQ + kk)) * KVD + kvh * HD + cb * 16 + l15;
      short8 vfr;
#pragma unroll
      for (int j = 0; j < 8; ++j) vfr[j] = (short)vp[(size_t)j * KVD];
      acc = __builtin_amdgcn_mfma_f32_16x16x32_bf16(pa, vfr, acc, 0, 0, 0);
    }
#pragma unroll
    for (int r = 0; r < 4; ++r) {
      ao[((size_t)(b * SEQ + qrow0 + lhi * 4 + r)) * DIM + h * HD + cb * 16 + l15] = f2bf(acc[r]);
    }
  }
}

// ---------------------------------------------------------------- zero counts
__global__ void zero_cnt_kernel(int* __restrict__ cnt) {
  if (threadIdx.x < NE) cnt[threadIdx.x] = 0;
}

// ---------------------------------------------------------------- router (top-2, fp32 input + fp64 accum)
// Reads x2 (fp32) + ln2 weight directly so the discrete top-2 decision is not
// perturbed by bf16 rounding (bf16 h2 flips ~1% of tokens' expert pair).
__global__ void __launch_bounds__(64) router_kernel(const float* __restrict__ x2,
                                                    const float* __restrict__ ln2w,
                                                    const float* __restrict__ rw,
                                                    float* __restrict__ wts,
                                                    int* __restrict__ cnt,
                                                    int* __restrict__ lists) {
  int t = blockIdx.x, lane = threadIdx.x;
  const float* xr = x2 + (size_t)t * DIM;
  float xs[16];
  double ssq = 0.0;
#pragma unroll
  for (int j = 0; j < 16; ++j) {
    xs[j] = xr[lane + j * 64];
    ssq += (double)xs[j] * xs[j];
  }
  for (int o = 32; o; o >>= 1) ssq += __shfl_xor(ssq, o);
  double r = rsqrt(ssq * (1.0 / DIM) + 1e-6);
  double p[NE] = {};
#pragma unroll
  for (int j = 0; j < 16; ++j) {
    int i = lane + j * 64;
    double hv = (double)xs[j] * r * (double)ln2w[i];
    const float* rwp = rw + (size_t)i * NE;
#pragma unroll
    for (int e = 0; e < NE; ++e) p[e] += hv * (double)rwp[e];
  }
  for (int o = 32; o; o >>= 1) {
#pragma unroll
    for (int e = 0; e < NE; ++e) p[e] += __shfl_xor(p[e], o);
  }
  if (lane == 0) {
    int i1 = 0;
    for (int e = 1; e < NE; ++e)
      if (p[e] > p[i1]) i1 = e;
    int i2 = (i1 == 0) ? 1 : 0;
    for (int e = 0; e < NE; ++e)
      if (e != i1 && p[e] > p[i2]) i2 = e;
    double m = fmax(p[i1], p[i2]);
    double e1 = exp(p[i1] - m), e2 = exp(p[i2] - m);
    double inv = 1.0 / (e1 + e2);
    wts[t * 2] = (float)(e1 * inv);
    wts[t * 2 + 1] = (float)(e2 * inv);
    int pos1 = atomicAdd(&cnt[i1], 1);
    lists[i1 * NT + pos1] = t * 2;
    int pos2 = atomicAdd(&cnt[i2], 1);
    lists[i2 * NT + pos2] = t * 2 + 1;
  }
}

// ---------------------------------------------------------------- MoE GEMM1 (gate+up fused, SwiGLU)
__global__ void __launch_bounds__(256) moe_gemm1(
    const unsigned short* __restrict__ h2,
    const float* __restrict__ wg, const float* __restrict__ wu,
    const float* __restrict__ wts, const int* __restrict__ cnt, const int* __restrict__ lists,
    unsigned short* __restrict__ act) {
  int e = blockIdx.z;
  int count = cnt[e];
  int m0 = blockIdx.y * 64;
  if (count <= 0 || m0 >= count) return;
  int n0 = blockIdx.x * 64;
  const int* lst = lists + e * NT;
  const float* Bg = wg + (size_t)e * DIM * MDIM;
  const float* Bu = wu + (size_t)e * DIM * MDIM;

  __shared__ unsigned short As[64][40];
  __shared__ unsigned short Bgs[64][40];
  __shared__ unsigned short Bus[64][40];

  int tid = threadIdx.x, wave = tid >> 6, lane = tid & 63;
  f32x4 accg[4] = {};
  f32x4 accu[4] = {};

  int sr = tid >> 2, skc = (tid & 3) * 8;
  int mrow_s = m0 + sr;
  int pid_s = lst[mrow_s < count ? mrow_s : count - 1];
  const unsigned short* Aptr = h2 + (size_t)(pid_s >> 1) * DIM + skc;
  int snc = (tid & 15) * 4, skr = tid >> 4;

  for (int k0 = 0; k0 < DIM; k0 += 32) {
    __syncthreads();
    *(uint4*)&As[sr][skc] = *(const uint4*)(Aptr + k0);
#pragma unroll
    for (int p = 0; p < 2; ++p) {
      int kr = skr + p * 16;
      size_t boff = (size_t)(k0 + kr) * MDIM + n0 + snc;
      float4 vg = *(const float4*)(Bg + boff);
      float4 vu = *(const float4*)(Bu + boff);
      Bgs[snc + 0][kr] = f2bf(vg.x); Bgs[snc + 1][kr] = f2bf(vg.y);
      Bgs[snc + 2][kr] = f2bf(vg.z); Bgs[snc + 3][kr] = f2bf(vg.w);
      Bus[snc + 0][kr] = f2bf(vu.x); Bus[snc + 1][kr] = f2bf(vu.y);
      Bus[snc + 2][kr] = f2bf(vu.z); Bus[snc + 3][kr] = f2bf(vu.w);
    }
    __syncthreads();
    short8 a = *(const short8*)&As[wave * 16 + (lane & 15)][(lane >> 4) * 8];
#pragma unroll
    for (int cb = 0; cb < 4; ++cb) {
      short8 bg = *(const short8*)&Bgs[cb * 16 + (lane & 15)][(lane >> 4) * 8];
      short8 bu = *(const short8*)&Bus[cb * 16 + (lane & 15)][(lane >> 4) * 8];
      accg[cb] = __builtin_amdgcn_mfma_f32_16x16x32_bf16(a, bg, accg[cb], 0, 0, 0);
      accu[cb] = __builtin_amdgcn_mfma_f32_16x16x32_bf16(a, bu, accu[cb], 0, 0, 0);
    }
  }
  int col = lane & 15;
#pragma unroll
  for (int r = 0; r < 4; ++r) {
    int mrow = m0 + wave * 16 + ((lane >> 4) << 2) + r;
    if (mrow >= count) continue;
    int pid = lst[mrow];
    float wgt = wts[pid];
#pragma unroll
    for (int cb = 0; cb < 4; ++cb) {
      float g = accg[cb][r], u = accu[cb][r];
      float s = 1.f / (1.f + __expf(-g));
      act[(size_t)pid * MDIM + n0 + cb * 16 + col] = f2bf(g * s * u * wgt);
    }
  }
}

// ---------------------------------------------------------------- combine
__global__ void __launch_bounds__(256) combine_kernel(const float* __restrict__ x2,
                                                      const float* __restrict__ part,
                                                      float* __restrict__ out) {
  size_t idx = ((size_t)blockIdx.x * 256 + threadIdx.x) * 4;
  size_t t = idx >> 10;
  size_t d = idx & 1023;
  float4 a = *(const float4*)(x2 + idx);
  float4 b = *(const float4*)(part + (t * 2) * DIM + d);
  float4 c = *(const float4*)(part + (t * 2 + 1) * DIM + d);
  float4 o;
  o.x = a.x + b.x + c.x;
  o.y = a.y + b.y + c.y;
  o.z = a.z + b.z + c.z;
  o.w = a.w + b.w + c.w;
  *(float4*)(out + idx) = o;
}

// ---------------------------------------------------------------- launch
extern "C" void kernel_launch(void* const* d_in, const int* in_sizes, int n_in,
                              void* d_out, int out_size, void* d_ws, size_t ws_size,
                              hipStream_t stream) {
  const float* x   = (const float*)d_in[0];
  const float* ln1 = (const float*)d_in[1];
  const float* ln2 = (const float*)d_in[2];
  const float* wq  = (const float*)d_in[3];
  const float* wk  = (const float*)d_in[4];
  const float* wv  = (const float*)d_in[5];
  const float* wo  = (const float*)d_in[6];
  const float* rw  = (const float*)d_in[7];
  const float* wg  = (const float*)d_in[8];
  const float* wu  = (const float*)d_in[9];
  const float* wd  = (const float*)d_in[10];
  float* out = (float*)d_out;

  char* ws = (char*)d_ws;
  size_t off = 0;
  auto alloc = [&](size_t n) {
    void* p = ws + off;
    off += (n + 255) & ~(size_t)255;
    return p;
  };
  unsigned short* h1    = (unsigned short*)alloc((size_t)NT * DIM * 2);
  unsigned short* qbuf  = (unsigned short*)alloc((size_t)NT * DIM * 2);
  unsigned short* kbuf  = (unsigned short*)alloc((size_t)NT * KVD * 2);
  unsigned short* vbuf  = (unsigned short*)alloc((size_t)NT * KVD * 2);
  unsigned short* aob   = (unsigned short*)alloc((size_t)NT * DIM * 2);
  float*          x2    = (float*)alloc((size_t)NT * DIM * 4);
  unsigned short* h2    = (unsigned short*)alloc((size_t)NT * DIM * 2);
  unsigned short* act   = (unsigned short*)alloc((size_t)2 * NT * MDIM * 2);
  float*          part  = (float*)alloc((size_t)2 * NT * DIM * 4);
  float*          wtsb  = (float*)alloc((size_t)2 * NT * 4);
  int*            cntb  = (int*)alloc(NE * 4);
  int*            listsb= (int*)alloc((size_t)NE * NT * 4);

  // 1. rmsnorm1
  rmsnorm_kernel<<<NT, 256, 0, stream>>>(x, ln1, h1);

  // 2. QKV GEMMs (bf16 out)
  gemm_kernel<0, 0><<<dim3(DIM / 64, NT / 64, 1), 256, 0, stream>>>(
      h1, DIM, wq, DIM, 0, qbuf, DIM, nullptr, NT, DIM, nullptr, nullptr);
  gemm_kernel<0, 0><<<dim3(KVD / 64, NT / 64, 1), 256, 0, stream>>>(
      h1, DIM, wk, KVD, 0, kbuf, KVD, nullptr, NT, DIM, nullptr, nullptr);
  gemm_kernel<0, 0><<<dim3(KVD / 64, NT / 64, 1), 256, 0, stream>>>(
      h1, DIM, wv, KVD, 0, vbuf, KVD, nullptr, NT, DIM, nullptr, nullptr);

  // 3. RoPE in place on q,k
  rope_kernel<<<(NT * (NH + NKV) * 32) / 256, 256, 0, stream>>>(qbuf, kbuf);

  // 4. attention
  attn_kernel<<<NT * NH / 16, 64, 0, stream>>>(qbuf, kbuf, vbuf, aob);

  // 5. out-proj + residual -> x2 (fp32)
  gemm_kernel<0, 1><<<dim3(DIM / 64, NT / 64, 1), 256, 0, stream>>>(
      aob, DIM, wo, DIM, 0, x2, DIM, x, NT, DIM, nullptr, nullptr);

  // 6. rmsnorm2 (bf16 h2 for the expert GEMM A-inputs)
  rmsnorm_kernel<<<NT, 256, 0, stream>>>(x2, ln2, h2);

  // 7. router (fp32 path; zero counts first)
  zero_cnt_kernel<<<1, 64, 0, stream>>>(cntb);
  router_kernel<<<NT, 64, 0, stream>>>(x2, ln2, rw, wtsb, cntb, listsb);

  // 8. MoE gate/up + SwiGLU -> act (bf16, indexed by pairId)
  moe_gemm1<<<dim3(MDIM / 64, NT / 64, NE), 256, 0, stream>>>(
      h2, wg, wu, wtsb, cntb, listsb, act);

  // 9. MoE down -> part (fp32, indexed by pairId)
  gemm_kernel<2, 2><<<dim3(DIM / 64, NT / 64, NE), 256, 0, stream>>>(
      act, MDIM, wd, DIM, (size_t)MDIM * DIM, part, DIM, nullptr, 0, MDIM, listsb, cntb);

  // 10. combine: out = x2 + part[2t] + part[2t+1]
  combine_kernel<<<(NT * DIM) / 1024, 256, 0, stream>>>(x2, part, out);
}

// Round 3
// 884.831 us; speedup vs baseline: 1.3258x; 1.3258x over previous
//
#include <hip/hip_runtime.h>

typedef __attribute__((ext_vector_type(8))) short short8;
typedef __attribute__((ext_vector_type(4))) float f32x4;

#define DI static __device__ __forceinline__

DI unsigned short f2bf(float f) {
  unsigned u = __builtin_bit_cast(unsigned, f);
  u += 0x7fffu + ((u >> 16) & 1u);
  return (unsigned short)(u >> 16);
}
DI float bf2f(unsigned short b) {
  unsigned u = ((unsigned)b) << 16;
  return __builtin_bit_cast(float, u);
}

static constexpr int NT   = 2048;   // B*S tokens
static constexpr int SEQ  = 1024;
static constexpr int DIM  = 1024;
static constexpr int NH   = 16;
static constexpr int NKV  = 8;
static constexpr int HD   = 64;
static constexpr int KVD  = NKV * HD;  // 512
static constexpr int MDIM = 3584;
static constexpr int NE   = 8;

// ---------------------------------------------------------------- rmsnorm
__global__ void __launch_bounds__(256) rmsnorm_kernel(const float* __restrict__ x,
                                                      const float* __restrict__ w,
                                                      unsigned short* __restrict__ out) {
  int row = blockIdx.x;
  const float* xr = x + (size_t)row * DIM;
  int i = threadIdx.x * 4;
  float4 v = *(const float4*)(xr + i);
  float s = v.x * v.x + v.y * v.y + v.z * v.z + v.w * v.w;
  for (int o = 32; o; o >>= 1) s += __shfl_xor(s, o);
  __shared__ float red[4];
  if ((threadIdx.x & 63) == 0) red[threadIdx.x >> 6] = s;
  __syncthreads();
  s = red[0] + red[1] + red[2] + red[3];
  float r = rsqrtf(s * (1.0f / DIM) + 1e-6f);
  float4 wv = *(const float4*)(w + i);
  ushort4 o4;
  o4.x = f2bf(v.x * r * wv.x);
  o4.y = f2bf(v.y * r * wv.y);
  o4.z = f2bf(v.z * r * wv.z);
  o4.w = f2bf(v.w * r * wv.w);
  *(ushort4*)(out + (size_t)row * DIM + i) = o4;
}

// ---------------------------------------------------------------- big-tile GEMM
// A: bf16 [M x K] (rows optionally gathered), B: fp32 [K x N] row-major (bf16-
// converted in staging). W waves (W*64 thr), tile M = W*32, N = (W==16?128:64).
// LDS XOR-swizzle (((row>>3)&3)<<3 on k-elements) keeps ds_read_b128 at floor.
// GATHER: 0 none; 1 A-row=lst[]>>1, C-row=lst[]; 2 A-row=C-row=lst[].
// EPI: 0 bf16 C; 1 fp32 C = acc + resid; 2 fp32 C = acc.
template <int GATHER, int EPI, int W>
__global__ void __launch_bounds__(W * 64) gemm512_kernel(
    const unsigned short* __restrict__ A, int lda,
    const float* __restrict__ B, int ldb, size_t b_estride,
    void* __restrict__ Cv, int ldc,
    const float* __restrict__ resid,
    int M, int K,
    const int* __restrict__ lists, const int* __restrict__ cnt) {
  constexpr int MT = W * 32;
  constexpr int NTW = (W == 16) ? 128 : 64;
  constexpr int NNT = NTW / 16;

  int e = blockIdx.z;
  int count = M;
  const int* lst = nullptr;
  const float* Bp = B;
  if (GATHER != 0) {
    count = cnt[e];
    if (count <= 0) return;
    lst = lists + e * NT;
    Bp = B + b_estride * (size_t)e;
  }
  int m0 = blockIdx.y * MT;
  if (m0 >= count) return;
  int n0 = blockIdx.x * NTW;

  __shared__ unsigned short As[MT * 32];
  __shared__ unsigned short Bs[NTW * 32];

  int tid = threadIdx.x;
  int wv = tid >> 6, lane = tid & 63, l15 = lane & 15, lhi = lane >> 4;

  // ---- A staging addresses (per thread: 2 x uint4 = one 32-k row slice)
  int am = tid >> 1, akc = (tid & 1) * 16;
  int arow;
  {
    int mr = m0 + am;
    if (mr > count - 1) mr = count - 1;
    if (GATHER == 0) arow = mr;
    else {
      int pid = lst[mr];
      arow = (GATHER == 1) ? (pid >> 1) : pid;
    }
  }
  const unsigned short* Ap = A + (size_t)arow * lda + akc;
  int aswz = ((am >> 3) & 3) << 3;
  int aw0 = am * 32 + (akc ^ aswz);
  int aw1 = am * 32 + ((akc + 8) ^ aswz);

  // ---- B staging addresses (float4 per thread, transposed scalar writes)
  int bn, bkr;
  bool bact;
  if (W == 16) { bn = (tid & 31) * 4; bkr = tid >> 5; bact = true; }
  else         { bn = (tid & 15) * 4; bkr = tid >> 4; bact = (tid < 512); }
  const float* Bpp = Bp + (size_t)bkr * ldb + n0 + bn;
  int bw[4];
#pragma unroll
  for (int j = 0; j < 4; ++j)
    bw[j] = (bn + j) * 32 + (bkr ^ ((((bn + j) >> 3) & 3) << 3));

  // ---- fragment read addresses
  int afr[2], bfr[NNT];
#pragma unroll
  for (int mt = 0; mt < 2; ++mt) {
    int m = wv * 32 + mt * 16 + l15;
    afr[mt] = m * 32 + ((lhi * 8) ^ (((m >> 3) & 3) << 3));
  }
#pragma unroll
  for (int nt = 0; nt < NNT; ++nt) {
    int n = nt * 16 + l15;
    bfr[nt] = n * 32 + ((lhi * 8) ^ (((n >> 3) & 3) << 3));
  }

  f32x4 acc[2][NNT] = {};

  for (int k0 = 0; k0 < K; k0 += 32) {
    __syncthreads();
    uint4 a0 = *(const uint4*)(Ap + k0);
    uint4 a1 = *(const uint4*)(Ap + k0 + 8);
    *(uint4*)&As[aw0] = a0;
    *(uint4*)&As[aw1] = a1;
    if (bact) {
      float4 v = *(const float4*)(Bpp + (size_t)k0 * ldb);
      Bs[bw[0]] = f2bf(v.x);
      Bs[bw[1]] = f2bf(v.y);
      Bs[bw[2]] = f2bf(v.z);
      Bs[bw[3]] = f2bf(v.w);
    }
    __syncthreads();
    short8 af0 = *(const short8*)&As[afr[0]];
    short8 af1 = *(const short8*)&As[afr[1]];
#pragma unroll
    for (int nt = 0; nt < NNT; ++nt) {
      short8 bf = *(const short8*)&Bs[bfr[nt]];
      acc[0][nt] = __builtin_amdgcn_mfma_f32_16x16x32_bf16(af0, bf, acc[0][nt], 0, 0, 0);
      acc[1][nt] = __builtin_amdgcn_mfma_f32_16x16x32_bf16(af1, bf, acc[1][nt], 0, 0, 0);
    }
  }

#pragma unroll
  for (int mt = 0; mt < 2; ++mt) {
#pragma unroll
    for (int r = 0; r < 4; ++r) {
      int mr = m0 + wv * 32 + mt * 16 + lhi * 4 + r;
      if (mr >= count) continue;
      size_t crow = (GATHER == 0) ? (size_t)mr : (size_t)lst[mr];
#pragma unroll
      for (int nt = 0; nt < NNT; ++nt) {
        int n = n0 + nt * 16 + l15;
        float val = acc[mt][nt][r];
        if (EPI == 0)
          ((unsigned short*)Cv)[crow * ldc + n] = f2bf(val);
        else if (EPI == 1)
          ((float*)Cv)[crow * ldc + n] = val + resid[crow * ldc + n];
        else
          ((float*)Cv)[crow * ldc + n] = val;
      }
    }
  }
}

// ---------------------------------------------------------------- RoPE (in-place, bf16 q/k)
__global__ void __launch_bounds__(256) rope_kernel(unsigned short* __restrict__ qb,
                                                   unsigned short* __restrict__ kb) {
  int g = blockIdx.x * 256 + threadIdx.x;
  int i = g & 31;
  int hh = (g >> 5) % (NH + NKV);
  int tok = g / (32 * (NH + NKV));
  if (tok >= NT) return;
  int s = tok & (SEQ - 1);
  float inv = exp2f((float)i * (-13.287712379549449f / 32.0f));
  float ang = (float)s * inv;
  float sn = sinf(ang);
  float c  = cosf(ang);
  unsigned short* ptr = (hh < NH) ? (qb + (size_t)tok * DIM + hh * HD)
                                  : (kb + (size_t)tok * KVD + (hh - NH) * HD);
  float a = bf2f(ptr[i]), b2 = bf2f(ptr[i + 32]);
  ptr[i]      = f2bf(a * c - b2 * sn);
  ptr[i + 32] = f2bf(b2 * c + a * sn);
}

// ---------------------------------------------------------------- flash attention
// 1 wave / (b, head, 16 q-rows). Online softmax in registers; P staged through
// a 2KB conflict-free XOR-swizzled LDS stash to convert C-layout -> A-layout.
__global__ void __launch_bounds__(64) attn_kernel(const unsigned short* __restrict__ qb,
                                                  const unsigned short* __restrict__ kb,
                                                  const unsigned short* __restrict__ vb,
                                                  unsigned short* __restrict__ ao) {
  __shared__ unsigned short Ps[16 * 64];
  int bid = blockIdx.x;
  int qt = bid & 63;
  int h = (bid >> 6) & 15;
  int b = bid >> 10;
  int lane = threadIdx.x, l15 = lane & 15, lhi = lane >> 4;
  int q0 = qt * 16, kvh = h >> 1;

  const unsigned short* qp = qb + ((size_t)(b * SEQ + q0 + l15)) * DIM + h * HD + lhi * 8;
  short8 aq0 = *(const short8*)qp;
  short8 aq1 = *(const short8*)(qp + 32);

  float m[4] = {-1e30f, -1e30f, -1e30f, -1e30f};
  float l[4] = {0.f, 0.f, 0.f, 0.f};
  f32x4 accO[4] = {};

  int nkb = (qt >> 2) + 1;
  for (int kb_ = 0; kb_ < nkb; ++kb_) {
    int kbase = kb_ * 64;
    f32x4 s[4];
#pragma unroll
    for (int ct = 0; ct < 4; ++ct) {
      const unsigned short* kp =
          kb + ((size_t)(b * SEQ + kbase + ct * 16 + l15)) * KVD + kvh * HD + lhi * 8;
      short8 k0v = *(const short8*)kp;
      short8 k1v = *(const short8*)(kp + 32);
      f32x4 a = {};
      a = __builtin_amdgcn_mfma_f32_16x16x32_bf16(aq0, k0v, a, 0, 0, 0);
      a = __builtin_amdgcn_mfma_f32_16x16x32_bf16(aq1, k1v, a, 0, 0, 0);
      int kpos = kbase + ct * 16 + l15;
#pragma unroll
      for (int r = 0; r < 4; ++r) {
        float v = a[r] * 0.125f;
        if (kpos > q0 + lhi * 4 + r) v = -1e30f;
        s[ct][r] = v;
      }
    }
    float nm[4], al[4], rs[4];
#pragma unroll
    for (int r = 0; r < 4; ++r) {
      float mb = fmaxf(fmaxf(s[0][r], s[1][r]), fmaxf(s[2][r], s[3][r]));
      mb = fmaxf(mb, __shfl_xor(mb, 1));
      mb = fmaxf(mb, __shfl_xor(mb, 2));
      mb = fmaxf(mb, __shfl_xor(mb, 4));
      mb = fmaxf(mb, __shfl_xor(mb, 8));
      nm[r] = fmaxf(m[r], mb);
      al[r] = __expf(m[r] - nm[r]);
      m[r] = nm[r];
      rs[r] = 0.f;
    }
#pragma unroll
    for (int ct = 0; ct < 4; ++ct) {
#pragma unroll
      for (int r = 0; r < 4; ++r) {
        float p = __expf(s[ct][r] - nm[r]);
        rs[r] += p;
        int q = lhi * 4 + r;
        Ps[q * 64 + ((ct * 16 + l15) ^ (lhi << 4))] = f2bf(p);
      }
    }
#pragma unroll
    for (int r = 0; r < 4; ++r) {
      rs[r] += __shfl_xor(rs[r], 1);
      rs[r] += __shfl_xor(rs[r], 2);
      rs[r] += __shfl_xor(rs[r], 4);
      rs[r] += __shfl_xor(rs[r], 8);
      l[r] = l[r] * al[r] + rs[r];
    }
#pragma unroll
    for (int dt = 0; dt < 4; ++dt)
#pragma unroll
      for (int r = 0; r < 4; ++r) accO[dt][r] *= al[r];

    int pswz = (l15 >> 2) << 4;
    short8 ap0 = *(const short8*)&Ps[l15 * 64 + ((lhi * 8) ^ pswz)];
    short8 ap1 = *(const short8*)&Ps[l15 * 64 + ((32 + lhi * 8) ^ pswz)];
#pragma unroll
    for (int dt = 0; dt < 4; ++dt) {
#pragma unroll
      for (int ks = 0; ks < 2; ++ks) {
        const unsigned short* vp =
            vb + ((size_t)(b * SEQ + kbase + ks * 32 + lhi * 8)) * KVD + kvh * HD + dt * 16 + l15;
        short8 vf;
#pragma unroll
        for (int j = 0; j < 8; ++j) vf[j] = (short)vp[(size_t)j * KVD];
        accO[dt] = __builtin_amdgcn_mfma_f32_16x16x32_bf16(ks ? ap1 : ap0, vf, accO[dt], 0, 0, 0);
      }
    }
  }
  float invl[4];
#pragma unroll
  for (int r = 0; r < 4; ++r) invl[r] = 1.f / l[r];
#pragma unroll
  for (int dt = 0; dt < 4; ++dt)
#pragma unroll
    for (int r = 0; r < 4; ++r)
      ao[((size_t)(b * SEQ + q0 + lhi * 4 + r)) * DIM + h * HD + dt * 16 + l15] =
          f2bf(accO[dt][r] * invl[r]);
}

// ---------------------------------------------------------------- zero counts
__global__ void zero_cnt_kernel(int* __restrict__ cnt) {
  if (threadIdx.x < NE) cnt[threadIdx.x] = 0;
}

// ---------------------------------------------------------------- router (top-2, fp32 + fp64 accum)
__global__ void __launch_bounds__(64) router_kernel(const float* __restrict__ x2,
                                                    const float* __restrict__ ln2w,
                                                    const float* __restrict__ rw,
                                                    float* __restrict__ wts,
                                                    int* __restrict__ cnt,
                                                    int* __restrict__ lists) {
  int t = blockIdx.x, lane = threadIdx.x;
  const float* xr = x2 + (size_t)t * DIM;
  float xs[16];
  double ssq = 0.0;
#pragma unroll
  for (int j = 0; j < 16; ++j) {
    xs[j] = xr[lane + j * 64];
    ssq += (double)xs[j] * xs[j];
  }
  for (int o = 32; o; o >>= 1) ssq += __shfl_xor(ssq, o);
  double r = rsqrt(ssq * (1.0 / DIM) + 1e-6);
  double p[NE] = {};
#pragma unroll
  for (int j = 0; j < 16; ++j) {
    int i = lane + j * 64;
    double hv = (double)xs[j] * r * (double)ln2w[i];
    const float* rwp = rw + (size_t)i * NE;
#pragma unroll
    for (int e = 0; e < NE; ++e) p[e] += hv * (double)rwp[e];
  }
  for (int o = 32; o; o >>= 1) {
#pragma unroll
    for (int e = 0; e < NE; ++e) p[e] += __shfl_xor(p[e], o);
  }
  if (lane == 0) {
    int i1 = 0;
    for (int e = 1; e < NE; ++e)
      if (p[e] > p[i1]) i1 = e;
    int i2 = (i1 == 0) ? 1 : 0;
    for (int e = 0; e < NE; ++e)
      if (e != i1 && p[e] > p[i2]) i2 = e;
    double mx = fmax(p[i1], p[i2]);
    double e1 = exp(p[i1] - mx), e2 = exp(p[i2] - mx);
    double inv = 1.0 / (e1 + e2);
    wts[t * 2] = (float)(e1 * inv);
    wts[t * 2 + 1] = (float)(e2 * inv);
    int pos1 = atomicAdd(&cnt[i1], 1);
    lists[i1 * NT + pos1] = t * 2;
    int pos2 = atomicAdd(&cnt[i2], 1);
    lists[i2 * NT + pos2] = t * 2 + 1;
  }
}

// ---------------------------------------------------------------- SwiGLU elementwise
__global__ void __launch_bounds__(256) swiglu_kernel(const unsigned short* __restrict__ g,
                                                     const unsigned short* __restrict__ u,
                                                     const float* __restrict__ wts,
                                                     unsigned short* __restrict__ act) {
  size_t i = ((size_t)blockIdx.x * 256 + threadIdx.x) * 8;
  int pid = (int)(i / MDIM);
  float w = wts[pid];
  short8 g8 = *(const short8*)(g + i);
  short8 u8 = *(const short8*)(u + i);
  short8 o8;
#pragma unroll
  for (int j = 0; j < 8; ++j) {
    float gv = bf2f((unsigned short)g8[j]);
    float uv = bf2f((unsigned short)u8[j]);
    float sv = gv / (1.f + __expf(-gv));
    o8[j] = (short)f2bf(sv * uv * w);
  }
  *(short8*)(act + i) = o8;
}

// ---------------------------------------------------------------- combine
__global__ void __launch_bounds__(256) combine_kernel(const float* __restrict__ x2,
                                                      const float* __restrict__ part,
                                                      float* __restrict__ out) {
  size_t idx = ((size_t)blockIdx.x * 256 + threadIdx.x) * 4;
  size_t t = idx >> 10;
  size_t d = idx & 1023;
  float4 a = *(const float4*)(x2 + idx);
  float4 b = *(const float4*)(part + (t * 2) * DIM + d);
  float4 c = *(const float4*)(part + (t * 2 + 1) * DIM + d);
  float4 o;
  o.x = a.x + b.x + c.x;
  o.y = a.y + b.y + c.y;
  o.z = a.z + b.z + c.z;
  o.w = a.w + b.w + c.w;
  *(float4*)(out + idx) = o;
}

// ---------------------------------------------------------------- launch
extern "C" void kernel_launch(void* const* d_in, const int* in_sizes, int n_in,
                              void* d_out, int out_size, void* d_ws, size_t ws_size,
                              hipStream_t stream) {
  const float* x   = (const float*)d_in[0];
  const float* ln1 = (const float*)d_in[1];
  const float* ln2 = (const float*)d_in[2];
  const float* wq  = (const float*)d_in[3];
  const float* wk  = (const float*)d_in[4];
  const float* wv  = (const float*)d_in[5];
  const float* wo  = (const float*)d_in[6];
  const float* rw  = (const float*)d_in[7];
  const float* wg  = (const float*)d_in[8];
  const float* wu  = (const float*)d_in[9];
  const float* wd  = (const float*)d_in[10];
  float* out = (float*)d_out;

  char* ws = (char*)d_ws;
  size_t off = 0;
  auto alloc = [&](size_t n) {
    void* p = ws + off;
    off += (n + 255) & ~(size_t)255;
    return p;
  };
  unsigned short* h1    = (unsigned short*)alloc((size_t)NT * DIM * 2);
  unsigned short* qbuf  = (unsigned short*)alloc((size_t)NT * DIM * 2);
  unsigned short* kbuf  = (unsigned short*)alloc((size_t)NT * KVD * 2);
  unsigned short* vbuf  = (unsigned short*)alloc((size_t)NT * KVD * 2);
  unsigned short* aob   = (unsigned short*)alloc((size_t)NT * DIM * 2);
  float*          x2    = (float*)alloc((size_t)NT * DIM * 4);
  unsigned short* h2    = (unsigned short*)alloc((size_t)NT * DIM * 2);
  unsigned short* gbuf  = (unsigned short*)alloc((size_t)2 * NT * MDIM * 2);
  unsigned short* ubuf  = (unsigned short*)alloc((size_t)2 * NT * MDIM * 2);
  float*          part  = (float*)alloc((size_t)2 * NT * DIM * 4);
  float*          wtsb  = (float*)alloc((size_t)2 * NT * 4);
  int*            cntb  = (int*)alloc(NE * 4);
  int*            listsb= (int*)alloc((size_t)NE * NT * 4);

  // 1. rmsnorm1
  rmsnorm_kernel<<<NT, 256, 0, stream>>>(x, ln1, h1);

  // 2. QKV GEMMs (bf16 out, M-tile 256)
  gemm512_kernel<0, 0, 8><<<dim3(DIM / 64, NT / 256, 1), 512, 0, stream>>>(
      h1, DIM, wq, DIM, 0, qbuf, DIM, nullptr, NT, DIM, nullptr, nullptr);
  gemm512_kernel<0, 0, 8><<<dim3(KVD / 64, NT / 256, 1), 512, 0, stream>>>(
      h1, DIM, wk, KVD, 0, kbuf, KVD, nullptr, NT, DIM, nullptr, nullptr);
  gemm512_kernel<0, 0, 8><<<dim3(KVD / 64, NT / 256, 1), 512, 0, stream>>>(
      h1, DIM, wv, KVD, 0, vbuf, KVD, nullptr, NT, DIM, nullptr, nullptr);

  // 3. RoPE in place on q,k
  rope_kernel<<<(NT * (NH + NKV) * 32) / 256, 256, 0, stream>>>(qbuf, kbuf);

  // 4. flash attention
  attn_kernel<<<NT * NH / 16, 64, 0, stream>>>(qbuf, kbuf, vbuf, aob);

  // 5. out-proj + residual -> x2 (fp32)
  gemm512_kernel<0, 1, 8><<<dim3(DIM / 64, NT / 256, 1), 512, 0, stream>>>(
      aob, DIM, wo, DIM, 0, x2, DIM, x, NT, DIM, nullptr, nullptr);

  // 6. rmsnorm2 (bf16 h2 for expert GEMM A-input)
  rmsnorm_kernel<<<NT, 256, 0, stream>>>(x2, ln2, h2);

  // 7. router (fp32/fp64 path)
  zero_cnt_kernel<<<1, 64, 0, stream>>>(cntb);
  router_kernel<<<NT, 64, 0, stream>>>(x2, ln2, rw, wtsb, cntb, listsb);

  // 8. MoE gate & up projections (M-tile 512; single-B each; B staged ~once)
  gemm512_kernel<1, 0, 16><<<dim3(MDIM / 128, 4, NE), 1024, 0, stream>>>(
      h2, DIM, wg, MDIM, (size_t)DIM * MDIM, gbuf, MDIM, nullptr, 0, DIM, listsb, cntb);
  gemm512_kernel<1, 0, 16><<<dim3(MDIM / 128, 4, NE), 1024, 0, stream>>>(
      h2, DIM, wu, MDIM, (size_t)DIM * MDIM, ubuf, MDIM, nullptr, 0, DIM, listsb, cntb);

  // 9. SwiGLU (in-place into gbuf)
  swiglu_kernel<<<(int)(((size_t)2 * NT * MDIM) / (256 * 8)), 256, 0, stream>>>(
      gbuf, ubuf, wtsb, gbuf);

  // 10. MoE down -> part (fp32, indexed by pairId)
  gemm512_kernel<2, 2, 16><<<dim3(DIM / 128, 4, NE), 1024, 0, stream>>>(
      gbuf, MDIM, wd, DIM, (size_t)MDIM * DIM, part, DIM, nullptr, 0, MDIM, listsb, cntb);

  // 11. combine: out = x2 + part[2t] + part[2t+1]
  combine_kernel<<<(NT * DIM) / 1024, 256, 0, stream>>>(x2, part, out);
}

// Round 4
// 593.362 us; speedup vs baseline: 1.9770x; 1.4912x over previous
//
#include <hip/hip_runtime.h>

typedef __attribute__((ext_vector_type(8))) short short8;
typedef __attribute__((ext_vector_type(4))) float f32x4;
typedef unsigned int u32;

#define DI static __device__ __forceinline__

DI unsigned short f2bf(float f) {
  unsigned u = __builtin_bit_cast(unsigned, f);
  u += 0x7fffu + ((u >> 16) & 1u);
  return (unsigned short)(u >> 16);
}
DI float bf2f(unsigned short b) {
  unsigned u = ((unsigned)b) << 16;
  return __builtin_bit_cast(float, u);
}

DI void gload16(const unsigned short* g, unsigned short* l) {
  __builtin_amdgcn_global_load_lds(
      (const __attribute__((address_space(1))) u32*)g,
      (__attribute__((address_space(3))) u32*)l, 16, 0, 0);
}

static constexpr int NT   = 2048;   // B*S tokens
static constexpr int SEQ  = 1024;
static constexpr int DIM  = 1024;
static constexpr int NH   = 16;
static constexpr int NKV  = 8;
static constexpr int HD   = 64;
static constexpr int MDIM = 3584;
static constexpr int NE   = 8;
static constexpr int QW   = 2048;   // fused qkv width
static constexpr int GUW  = 2 * MDIM;  // 7168

// ---------------------------------------------------------------- transpose+convert
// in: fp32 [R][C] (+ e*in_estride), out: bf16 [C][R] (+ e*out_estride).
// 64x64 tiles staged through LDS (pitch 66 to spread banks).
__global__ void __launch_bounds__(256) transpose_kernel(
    const float* __restrict__ in, unsigned short* __restrict__ out,
    int R, int C, size_t in_estride, size_t out_estride) {
  __shared__ unsigned short tl[64][66];
  int e = blockIdx.z;
  const float* ip = in + (size_t)e * in_estride;
  unsigned short* op = out + (size_t)e * out_estride;
  int c0 = blockIdx.x * 64, r0 = blockIdx.y * 64;
  int tid = threadIdx.x;
  {
    int lr = tid >> 4, lc = (tid & 15) * 4;
#pragma unroll
    for (int p = 0; p < 4; ++p) {
      int r = p * 16 + lr;
      float4 v = *(const float4*)(ip + (size_t)(r0 + r) * C + c0 + lc);
      tl[lc + 0][r] = f2bf(v.x);
      tl[lc + 1][r] = f2bf(v.y);
      tl[lc + 2][r] = f2bf(v.z);
      tl[lc + 3][r] = f2bf(v.w);
    }
  }
  __syncthreads();
  {
    int c = tid >> 2, rc = (tid & 3) * 16;
    unsigned short tmp[16];
#pragma unroll
    for (int j = 0; j < 8; ++j) {
      u32 w = *(const u32*)&tl[c][rc + j * 2];
      tmp[j * 2] = (unsigned short)w;
      tmp[j * 2 + 1] = (unsigned short)(w >> 16);
    }
    unsigned short* dst = op + (size_t)(c0 + c) * R + r0 + rc;
#pragma unroll
    for (int j = 0; j < 2; ++j)
      *(uint4*)(dst + j * 8) = *(const uint4*)&tmp[j * 8];
  }
}

// ---------------------------------------------------------------- rmsnorm
__global__ void __launch_bounds__(256) rmsnorm_kernel(const float* __restrict__ x,
                                                      const float* __restrict__ w,
                                                      unsigned short* __restrict__ out) {
  int row = blockIdx.x;
  const float* xr = x + (size_t)row * DIM;
  int i = threadIdx.x * 4;
  float4 v = *(const float4*)(xr + i);
  float s = v.x * v.x + v.y * v.y + v.z * v.z + v.w * v.w;
  for (int o = 32; o; o >>= 1) s += __shfl_xor(s, o);
  __shared__ float red[4];
  if ((threadIdx.x & 63) == 0) red[threadIdx.x >> 6] = s;
  __syncthreads();
  s = red[0] + red[1] + red[2] + red[3];
  float r = rsqrtf(s * (1.0f / DIM) + 1e-6f);
  float4 wv = *(const float4*)(w + i);
  ushort4 o4;
  o4.x = f2bf(v.x * r * wv.x);
  o4.y = f2bf(v.y * r * wv.y);
  o4.z = f2bf(v.z * r * wv.z);
  o4.w = f2bf(v.w * r * wv.w);
  *(ushort4*)(out + (size_t)row * DIM + i) = o4;
}

// ---------------------------------------------------------------- gemmT
// A: bf16 [M][K] (rows optionally gathered), B: bf16 [N][K] (pre-transposed).
// 256 thr / 4 waves; 128x128 tile; BK=32; double-buffered global_load_lds
// staging with 2-phase prefetch; chunk^(row&3) XOR swizzle (source+read).
// GATHER: 0 none; 1 A-row=lst[]>>1, C-row=lst[]; 2 A-row=C-row=lst[].
// EPI: 0 bf16 C; 1 fp32 C = acc + resid; 2 fp32 C = acc.
template <int GATHER, int EPI>
__global__ void __launch_bounds__(256) gemmT_kernel(
    const unsigned short* __restrict__ A, int lda,
    const unsigned short* __restrict__ B, int ldb, size_t b_estride,
    void* __restrict__ Cv, int ldc,
    const float* __restrict__ resid,
    int M, int K,
    const int* __restrict__ lists, const int* __restrict__ cnt) {
  int e = blockIdx.z;
  int count = M;
  const int* lst = nullptr;
  if (GATHER != 0) {
    count = cnt[e];
    if (count <= 0) return;
    lst = lists + e * NT;
    B += b_estride * (size_t)e;
  }
  int m0 = blockIdx.y * 128;
  if (m0 >= count) return;
  int n0 = blockIdx.x * 128;

  __shared__ unsigned short sA[2][128 * 32];
  __shared__ unsigned short sB[2][128 * 32];

  int tid = threadIdx.x, w = tid >> 6, lane = tid & 63;
  int l15 = lane & 15, lhi = lane >> 4;

  // staging sources: issue i covers rows i*64 + w*16 + (lane>>2); lane&3 is
  // the 16B chunk position; global chunk = pos ^ (row&3) (pre-swizzle).
  int srow = w * 16 + (lane >> 2);
  int schunk = ((lane & 3) ^ ((lane >> 2) & 3)) * 8;
  const unsigned short *aSrc0, *aSrc1, *bSrc0, *bSrc1;
  {
    int mr0 = m0 + srow, mr1 = m0 + 64 + srow;
    int ar0, ar1;
    if (GATHER == 0) { ar0 = mr0; ar1 = mr1; }
    else {
      int c0i = mr0 < count ? mr0 : count - 1;
      int c1i = mr1 < count ? mr1 : count - 1;
      int p0 = lst[c0i], p1 = lst[c1i];
      ar0 = (GATHER == 1) ? (p0 >> 1) : p0;
      ar1 = (GATHER == 1) ? (p1 >> 1) : p1;
    }
    aSrc0 = A + (size_t)ar0 * lda + schunk;
    aSrc1 = A + (size_t)ar1 * lda + schunk;
    bSrc0 = B + (size_t)(n0 + srow) * ldb + schunk;
    bSrc1 = B + (size_t)(n0 + 64 + srow) * ldb + schunk;
  }
  unsigned ldst = (unsigned)(w * 16) * 32;  // element offset of wave's chunk

#define STAGE(buf, k0)                                   \
  do {                                                   \
    gload16(aSrc0 + (k0), &sA[buf][ldst]);               \
    gload16(aSrc1 + (k0), &sA[buf][ldst + 64 * 32]);     \
    gload16(bSrc0 + (k0), &sB[buf][ldst]);               \
    gload16(bSrc1 + (k0), &sB[buf][ldst + 64 * 32]);     \
  } while (0)

  f32x4 acc[4][4] = {};
  int wm = w >> 1, wn = w & 1;
  int aoff[4], boff[4];
#pragma unroll
  for (int t = 0; t < 4; ++t) {
    int row = wm * 64 + t * 16 + l15;
    aoff[t] = row * 32 + ((lhi ^ (row & 3)) * 8);
    int col = wn * 64 + t * 16 + l15;
    boff[t] = col * 32 + ((lhi ^ (col & 3)) * 8);
  }

  int nsteps = K / 32;
  STAGE(0, 0);
  asm volatile("s_waitcnt vmcnt(0)" ::: "memory");
  __syncthreads();
  int cur = 0;
  for (int t = 0; t < nsteps; ++t) {
    if (t + 1 < nsteps) STAGE(cur ^ 1, (t + 1) * 32);
    short8 af[4], bfr[4];
#pragma unroll
    for (int q = 0; q < 4; ++q) {
      af[q] = *(const short8*)&sA[cur][aoff[q]];
      bfr[q] = *(const short8*)&sB[cur][boff[q]];
    }
#pragma unroll
    for (int mi = 0; mi < 4; ++mi)
#pragma unroll
      for (int ni = 0; ni < 4; ++ni)
        acc[mi][ni] =
            __builtin_amdgcn_mfma_f32_16x16x32_bf16(af[mi], bfr[ni], acc[mi][ni], 0, 0, 0);
    asm volatile("s_waitcnt vmcnt(0)" ::: "memory");
    __syncthreads();
    cur ^= 1;
  }
#undef STAGE

#pragma unroll
  for (int mi = 0; mi < 4; ++mi) {
#pragma unroll
    for (int r = 0; r < 4; ++r) {
      int mr = m0 + wm * 64 + mi * 16 + lhi * 4 + r;
      if (GATHER != 0 && mr >= count) continue;
      size_t crow = (GATHER != 0) ? (size_t)lst[mr] : (size_t)mr;
#pragma unroll
      for (int ni = 0; ni < 4; ++ni) {
        int n = n0 + wn * 64 + ni * 16 + l15;
        float val = acc[mi][ni][r];
        if (EPI == 0)
          ((unsigned short*)Cv)[crow * ldc + n] = f2bf(val);
        else if (EPI == 1)
          ((float*)Cv)[crow * ldc + n] = val + resid[crow * ldc + n];
        else
          ((float*)Cv)[crow * ldc + n] = val;
      }
    }
  }
}

// ---------------------------------------------------------------- RoPE (in-place on fused qkv)
__global__ void __launch_bounds__(256) rope_kernel(unsigned short* __restrict__ qkv) {
  int g = blockIdx.x * 256 + threadIdx.x;
  int i = g & 31;
  int hh = (g >> 5) % (NH + NKV);
  int tok = g / (32 * (NH + NKV));
  if (tok >= NT) return;
  int s = tok & (SEQ - 1);
  float inv = exp2f((float)i * (-13.287712379549449f / 32.0f));
  float ang = (float)s * inv;
  float sn = sinf(ang);
  float c = cosf(ang);
  int col = (hh < NH) ? hh * HD : DIM + (hh - NH) * HD;
  unsigned short* ptr = qkv + (size_t)tok * QW + col;
  float a = bf2f(ptr[i]), b2 = bf2f(ptr[i + 32]);
  ptr[i] = f2bf(a * c - b2 * sn);
  ptr[i + 32] = f2bf(b2 * c + a * sn);
}

// ---------------------------------------------------------------- flash attention
// 1 wave / (b, head, 16 q-rows). Online softmax in registers; P staged through
// a 2KB conflict-free XOR-swizzled LDS stash.
__global__ void __launch_bounds__(64) attn_kernel(const unsigned short* __restrict__ qkv,
                                                  unsigned short* __restrict__ ao) {
  __shared__ unsigned short Ps[16 * 64];
  int bid = blockIdx.x;
  int qt = bid & 63;
  int h = (bid >> 6) & 15;
  int b = bid >> 10;
  int lane = threadIdx.x, l15 = lane & 15, lhi = lane >> 4;
  int q0 = qt * 16, kvh = h >> 1;
  int kcol = DIM + kvh * HD, vcol = DIM + NKV * HD + kvh * HD;

  const unsigned short* qp = qkv + ((size_t)(b * SEQ + q0 + l15)) * QW + h * HD + lhi * 8;
  short8 aq0 = *(const short8*)qp;
  short8 aq1 = *(const short8*)(qp + 32);

  float m[4] = {-1e30f, -1e30f, -1e30f, -1e30f};
  float l[4] = {0.f, 0.f, 0.f, 0.f};
  f32x4 accO[4] = {};

  int nkb = (qt >> 2) + 1;
  for (int kb_ = 0; kb_ < nkb; ++kb_) {
    int kbase = kb_ * 64;
    f32x4 s[4];
#pragma unroll
    for (int ct = 0; ct < 4; ++ct) {
      const unsigned short* kp =
          qkv + ((size_t)(b * SEQ + kbase + ct * 16 + l15)) * QW + kcol + lhi * 8;
      short8 k0v = *(const short8*)kp;
      short8 k1v = *(const short8*)(kp + 32);
      f32x4 a = {};
      a = __builtin_amdgcn_mfma_f32_16x16x32_bf16(aq0, k0v, a, 0, 0, 0);
      a = __builtin_amdgcn_mfma_f32_16x16x32_bf16(aq1, k1v, a, 0, 0, 0);
      int kpos = kbase + ct * 16 + l15;
#pragma unroll
      for (int r = 0; r < 4; ++r) {
        float v = a[r] * 0.125f;
        if (kpos > q0 + lhi * 4 + r) v = -1e30f;
        s[ct][r] = v;
      }
    }
    float nm[4], al[4], rs[4];
#pragma unroll
    for (int r = 0; r < 4; ++r) {
      float mb = fmaxf(fmaxf(s[0][r], s[1][r]), fmaxf(s[2][r], s[3][r]));
      mb = fmaxf(mb, __shfl_xor(mb, 1));
      mb = fmaxf(mb, __shfl_xor(mb, 2));
      mb = fmaxf(mb, __shfl_xor(mb, 4));
      mb = fmaxf(mb, __shfl_xor(mb, 8));
      nm[r] = fmaxf(m[r], mb);
      al[r] = __expf(m[r] - nm[r]);
      m[r] = nm[r];
      rs[r] = 0.f;
    }
#pragma unroll
    for (int ct = 0; ct < 4; ++ct) {
#pragma unroll
      for (int r = 0; r < 4; ++r) {
        float p = __expf(s[ct][r] - nm[r]);
        rs[r] += p;
        int q = lhi * 4 + r;
        Ps[q * 64 + ((ct * 16 + l15) ^ (lhi << 4))] = f2bf(p);
      }
    }
#pragma unroll
    for (int r = 0; r < 4; ++r) {
      rs[r] += __shfl_xor(rs[r], 1);
      rs[r] += __shfl_xor(rs[r], 2);
      rs[r] += __shfl_xor(rs[r], 4);
      rs[r] += __shfl_xor(rs[r], 8);
      l[r] = l[r] * al[r] + rs[r];
    }
#pragma unroll
    for (int dt = 0; dt < 4; ++dt)
#pragma unroll
      for (int r = 0; r < 4; ++r) accO[dt][r] *= al[r];

    int pswz = (l15 >> 2) << 4;
    short8 ap0 = *(const short8*)&Ps[l15 * 64 + ((lhi * 8) ^ pswz)];
    short8 ap1 = *(const short8*)&Ps[l15 * 64 + ((32 + lhi * 8) ^ pswz)];
#pragma unroll
    for (int dt = 0; dt < 4; ++dt) {
#pragma unroll
      for (int ks = 0; ks < 2; ++ks) {
        const unsigned short* vp =
            qkv + ((size_t)(b * SEQ + kbase + ks * 32 + lhi * 8)) * QW + vcol + dt * 16 + l15;
        short8 vf;
#pragma unroll
        for (int j = 0; j < 8; ++j) vf[j] = (short)vp[(size_t)j * QW];
        accO[dt] = __builtin_amdgcn_mfma_f32_16x16x32_bf16(ks ? ap1 : ap0, vf, accO[dt], 0, 0, 0);
      }
    }
  }
  float invl[4];
#pragma unroll
  for (int r = 0; r < 4; ++r) invl[r] = 1.f / l[r];
#pragma unroll
  for (int dt = 0; dt < 4; ++dt)
#pragma unroll
    for (int r = 0; r < 4; ++r)
      ao[((size_t)(b * SEQ + q0 + lhi * 4 + r)) * DIM + h * HD + dt * 16 + l15] =
          f2bf(accO[dt][r] * invl[r]);
}

// ---------------------------------------------------------------- zero counts
__global__ void zero_cnt_kernel(int* __restrict__ cnt) {
  if (threadIdx.x < NE) cnt[threadIdx.x] = 0;
}

// ---------------------------------------------------------------- router (top-2, fp32 + fp64 accum)
__global__ void __launch_bounds__(64) router_kernel(const float* __restrict__ x2,
                                                    const float* __restrict__ ln2w,
                                                    const float* __restrict__ rw,
                                                    float* __restrict__ wts,
                                                    int* __restrict__ cnt,
                                                    int* __restrict__ lists) {
  int t = blockIdx.x, lane = threadIdx.x;
  const float* xr = x2 + (size_t)t * DIM;
  float xs[16];
  double ssq = 0.0;
#pragma unroll
  for (int j = 0; j < 16; ++j) {
    xs[j] = xr[lane + j * 64];
    ssq += (double)xs[j] * xs[j];
  }
  for (int o = 32; o; o >>= 1) ssq += __shfl_xor(ssq, o);
  double r = rsqrt(ssq * (1.0 / DIM) + 1e-6);
  double p[NE] = {};
#pragma unroll
  for (int j = 0; j < 16; ++j) {
    int i = lane + j * 64;
    double hv = (double)xs[j] * r * (double)ln2w[i];
    const float* rwp = rw + (size_t)i * NE;
#pragma unroll
    for (int e = 0; e < NE; ++e) p[e] += hv * (double)rwp[e];
  }
  for (int o = 32; o; o >>= 1) {
#pragma unroll
    for (int e = 0; e < NE; ++e) p[e] += __shfl_xor(p[e], o);
  }
  if (lane == 0) {
    int i1 = 0;
    for (int e = 1; e < NE; ++e)
      if (p[e] > p[i1]) i1 = e;
    int i2 = (i1 == 0) ? 1 : 0;
    for (int e = 0; e < NE; ++e)
      if (e != i1 && p[e] > p[i2]) i2 = e;
    double mx = fmax(p[i1], p[i2]);
    double e1 = exp(p[i1] - mx), e2 = exp(p[i2] - mx);
    double inv = 1.0 / (e1 + e2);
    wts[t * 2] = (float)(e1 * inv);
    wts[t * 2 + 1] = (float)(e2 * inv);
    int pos1 = atomicAdd(&cnt[i1], 1);
    lists[i1 * NT + pos1] = t * 2;
    int pos2 = atomicAdd(&cnt[i2], 1);
    lists[i2 * NT + pos2] = t * 2 + 1;
  }
}

// ---------------------------------------------------------------- SwiGLU elementwise
__global__ void __launch_bounds__(256) swiglu_kernel(const unsigned short* __restrict__ gu,
                                                     const float* __restrict__ wts,
                                                     unsigned short* __restrict__ act) {
  size_t i = ((size_t)blockIdx.x * 256 + threadIdx.x) * 8;
  int pid = (int)(i / MDIM);
  int mcol = (int)(i - (size_t)pid * MDIM);
  float w = wts[pid];
  const unsigned short* row = gu + (size_t)pid * GUW;
  short8 g8 = *(const short8*)(row + mcol);
  short8 u8 = *(const short8*)(row + MDIM + mcol);
  short8 o8;
#pragma unroll
  for (int j = 0; j < 8; ++j) {
    float gv = bf2f((unsigned short)g8[j]);
    float uv = bf2f((unsigned short)u8[j]);
    float sv = gv / (1.f + __expf(-gv));
    o8[j] = (short)f2bf(sv * uv * w);
  }
  *(short8*)(act + i) = o8;
}

// ---------------------------------------------------------------- combine
__global__ void __launch_bounds__(256) combine_kernel(const float* __restrict__ x2,
                                                      const float* __restrict__ part,
                                                      float* __restrict__ out) {
  size_t idx = ((size_t)blockIdx.x * 256 + threadIdx.x) * 4;
  size_t t = idx >> 10;
  size_t d = idx & 1023;
  float4 a = *(const float4*)(x2 + idx);
  float4 b = *(const float4*)(part + (t * 2) * DIM + d);
  float4 c = *(const float4*)(part + (t * 2 + 1) * DIM + d);
  float4 o;
  o.x = a.x + b.x + c.x;
  o.y = a.y + b.y + c.y;
  o.z = a.z + b.z + c.z;
  o.w = a.w + b.w + c.w;
  *(float4*)(out + idx) = o;
}

// ---------------------------------------------------------------- launch
extern "C" void kernel_launch(void* const* d_in, const int* in_sizes, int n_in,
                              void* d_out, int out_size, void* d_ws, size_t ws_size,
                              hipStream_t stream) {
  const float* x   = (const float*)d_in[0];
  const float* ln1 = (const float*)d_in[1];
  const float* ln2 = (const float*)d_in[2];
  const float* wq  = (const float*)d_in[3];
  const float* wk  = (const float*)d_in[4];
  const float* wv  = (const float*)d_in[5];
  const float* wo  = (const float*)d_in[6];
  const float* rw  = (const float*)d_in[7];
  const float* wg  = (const float*)d_in[8];
  const float* wu  = (const float*)d_in[9];
  const float* wd  = (const float*)d_in[10];
  float* out = (float*)d_out;

  char* p = (char*)d_ws;
  auto take = [&](size_t bytes) {
    char* q = p;
    p += (bytes + 255) & ~(size_t)255;
    return q;
  };
  // persistent
  unsigned short* wguT = (unsigned short*)take((size_t)NE * GUW * DIM * 2);   // 117 MB
  unsigned short* wdT  = (unsigned short*)take((size_t)NE * DIM * MDIM * 2);  // 59 MB
  float*          x2   = (float*)take((size_t)NT * DIM * 4);
  unsigned short* h2   = (unsigned short*)take((size_t)NT * DIM * 2);
  float*          part = (float*)take((size_t)2 * NT * DIM * 4);
  unsigned short* act  = (unsigned short*)take((size_t)2 * NT * MDIM * 2);
  float*          wtsb = (float*)take((size_t)2 * NT * 4);
  int*            cntb = (int*)take(NE * 4);
  int*            listsb = (int*)take((size_t)NE * NT * 4);
  // overlay region X: phase A (prep/attn) then phase B (gu)
  char* X = p;
  unsigned short* wqkvT = (unsigned short*)X;                 // [2048][1024]
  unsigned short* woT   = wqkvT + (size_t)QW * DIM;           // [1024][1024]
  unsigned short* h1    = woT + (size_t)DIM * DIM;
  unsigned short* qkv   = h1 + (size_t)NT * DIM;              // [NT][2048]
  unsigned short* aob   = qkv + (size_t)NT * QW;              // [NT][1024]
  unsigned short* gu    = (unsigned short*)X;                 // [2*NT][7168]

  // ---- weight prep: transpose+convert to bf16 [N][K]
  transpose_kernel<<<dim3(16, 16, 1), 256, 0, stream>>>(wq, wqkvT, DIM, DIM, 0, 0);
  transpose_kernel<<<dim3(8, 16, 1), 256, 0, stream>>>(wk, wqkvT + (size_t)DIM * DIM, DIM, 512, 0, 0);
  transpose_kernel<<<dim3(8, 16, 1), 256, 0, stream>>>(wv, wqkvT + (size_t)(DIM + 512) * DIM, DIM, 512, 0, 0);
  transpose_kernel<<<dim3(16, 16, 1), 256, 0, stream>>>(wo, woT, DIM, DIM, 0, 0);
  transpose_kernel<<<dim3(56, 16, NE), 256, 0, stream>>>(
      wg, wguT, DIM, MDIM, (size_t)DIM * MDIM, (size_t)GUW * DIM);
  transpose_kernel<<<dim3(56, 16, NE), 256, 0, stream>>>(
      wu, wguT + (size_t)MDIM * DIM, DIM, MDIM, (size_t)DIM * MDIM, (size_t)GUW * DIM);
  transpose_kernel<<<dim3(16, 56, NE), 256, 0, stream>>>(
      wd, wdT, MDIM, DIM, (size_t)MDIM * DIM, (size_t)DIM * MDIM);

  // ---- attention block
  rmsnorm_kernel<<<NT, 256, 0, stream>>>(x, ln1, h1);
  gemmT_kernel<0, 0><<<dim3(QW / 128, NT / 128, 1), 256, 0, stream>>>(
      h1, DIM, wqkvT, DIM, 0, qkv, QW, nullptr, NT, DIM, nullptr, nullptr);
  rope_kernel<<<(NT * (NH + NKV) * 32) / 256, 256, 0, stream>>>(qkv);
  attn_kernel<<<NT * NH / 16, 64, 0, stream>>>(qkv, aob);
  gemmT_kernel<0, 1><<<dim3(DIM / 128, NT / 128, 1), 256, 0, stream>>>(
      aob, DIM, woT, DIM, 0, x2, DIM, x, NT, DIM, nullptr, nullptr);

  // ---- MoE block
  rmsnorm_kernel<<<NT, 256, 0, stream>>>(x2, ln2, h2);
  zero_cnt_kernel<<<1, 64, 0, stream>>>(cntb);
  router_kernel<<<NT, 64, 0, stream>>>(x2, ln2, rw, wtsb, cntb, listsb);

  gemmT_kernel<1, 0><<<dim3(GUW / 128, 16, NE), 256, 0, stream>>>(
      h2, DIM, wguT, DIM, (size_t)GUW * DIM, gu, GUW, nullptr, 0, DIM, listsb, cntb);
  swiglu_kernel<<<(int)(((size_t)2 * NT * MDIM) / (256 * 8)), 256, 0, stream>>>(
      gu, wtsb, act);
  gemmT_kernel<2, 2><<<dim3(DIM / 128, 16, NE), 256, 0, stream>>>(
      act, MDIM, wdT, MDIM, (size_t)DIM * MDIM, part, DIM, nullptr, 0, MDIM, listsb, cntb);

  combine_kernel<<<(NT * DIM) / 1024, 256, 0, stream>>>(x2, part, out);
}

// Round 5
// 562.800 us; speedup vs baseline: 2.0844x; 1.0543x over previous
//
#include <hip/hip_runtime.h>

typedef __attribute__((ext_vector_type(8))) short short8;
typedef __attribute__((ext_vector_type(4))) float f32x4;
typedef unsigned int u32;

#define DI static __device__ __forceinline__

DI unsigned short f2bf(float f) {
  unsigned u = __builtin_bit_cast(unsigned, f);
  u += 0x7fffu + ((u >> 16) & 1u);
  return (unsigned short)(u >> 16);
}
DI float bf2f(unsigned short b) {
  unsigned u = ((unsigned)b) << 16;
  return __builtin_bit_cast(float, u);
}

DI void gload16(const unsigned short* g, unsigned short* l) {
  __builtin_amdgcn_global_load_lds(
      (const __attribute__((address_space(1))) u32*)g,
      (__attribute__((address_space(3))) u32*)l, 16, 0, 0);
}

static constexpr int NT   = 2048;   // B*S tokens
static constexpr int SEQ  = 1024;
static constexpr int DIM  = 1024;
static constexpr int NH   = 16;
static constexpr int NKV  = 8;
static constexpr int HD   = 64;
static constexpr int MDIM = 3584;
static constexpr int NE   = 8;
static constexpr int QW   = 2048;      // fused qkv width
static constexpr int GUW  = 2 * MDIM;  // 7168

// ---------------------------------------------------------------- transpose+convert
__global__ void __launch_bounds__(256) transpose_kernel(
    const float* __restrict__ in, unsigned short* __restrict__ out,
    int R, int C, size_t in_estride, size_t out_estride) {
  __shared__ unsigned short tl[64][66];
  int e = blockIdx.z;
  const float* ip = in + (size_t)e * in_estride;
  unsigned short* op = out + (size_t)e * out_estride;
  int c0 = blockIdx.x * 64, r0 = blockIdx.y * 64;
  int tid = threadIdx.x;
  {
    int lr = tid >> 4, lc = (tid & 15) * 4;
#pragma unroll
    for (int p = 0; p < 4; ++p) {
      int r = p * 16 + lr;
      float4 v = *(const float4*)(ip + (size_t)(r0 + r) * C + c0 + lc);
      tl[lc + 0][r] = f2bf(v.x);
      tl[lc + 1][r] = f2bf(v.y);
      tl[lc + 2][r] = f2bf(v.z);
      tl[lc + 3][r] = f2bf(v.w);
    }
  }
  __syncthreads();
  {
    int c = tid >> 2, rc = (tid & 3) * 16;
    unsigned short tmp[16];
#pragma unroll
    for (int j = 0; j < 8; ++j) {
      u32 w = *(const u32*)&tl[c][rc + j * 2];
      tmp[j * 2] = (unsigned short)w;
      tmp[j * 2 + 1] = (unsigned short)(w >> 16);
    }
    unsigned short* dst = op + (size_t)(c0 + c) * R + r0 + rc;
#pragma unroll
    for (int j = 0; j < 2; ++j)
      *(uint4*)(dst + j * 8) = *(const uint4*)&tmp[j * 8];
  }
}

// ---------------------------------------------------------------- rmsnorm
__global__ void __launch_bounds__(256) rmsnorm_kernel(const float* __restrict__ x,
                                                      const float* __restrict__ w,
                                                      unsigned short* __restrict__ out) {
  int row = blockIdx.x;
  const float* xr = x + (size_t)row * DIM;
  int i = threadIdx.x * 4;
  float4 v = *(const float4*)(xr + i);
  float s = v.x * v.x + v.y * v.y + v.z * v.z + v.w * v.w;
  for (int o = 32; o; o >>= 1) s += __shfl_xor(s, o);
  __shared__ float red[4];
  if ((threadIdx.x & 63) == 0) red[threadIdx.x >> 6] = s;
  __syncthreads();
  s = red[0] + red[1] + red[2] + red[3];
  float r = rsqrtf(s * (1.0f / DIM) + 1e-6f);
  float4 wv = *(const float4*)(w + i);
  ushort4 o4;
  o4.x = f2bf(v.x * r * wv.x);
  o4.y = f2bf(v.y * r * wv.y);
  o4.z = f2bf(v.z * r * wv.z);
  o4.w = f2bf(v.w * r * wv.w);
  *(ushort4*)(out + (size_t)row * DIM + i) = o4;
}

// ---------------------------------------------------------------- gemmT v2
// A: bf16 [M][K] (rows optionally gathered), B: bf16 [N][K] (pre-transposed).
// 256 thr / 4 waves; 128x128 tile; BK=32; 4-buffer LDS ring, 3-deep prefetch,
// counted vmcnt(8) + raw s_barrier (never drain to 0 in the main loop — T4).
// chunk^(row&3) XOR swizzle applied on global source AND LDS read (rule 21).
template <int GATHER, int EPI>
__global__ void __launch_bounds__(256) gemmT_kernel(
    const unsigned short* __restrict__ A, int lda,
    const unsigned short* __restrict__ B, int ldb, size_t b_estride,
    void* __restrict__ Cv, int ldc,
    const float* __restrict__ resid,
    int M, int K,
    const int* __restrict__ lists, const int* __restrict__ cnt) {
  int e = blockIdx.z;
  int count = M;
  const int* lst = nullptr;
  if (GATHER != 0) {
    count = cnt[e];
    if (count <= 0) return;
    lst = lists + e * NT;
    B += b_estride * (size_t)e;
  }
  int m0 = blockIdx.y * 128;
  if (m0 >= count) return;
  int n0 = blockIdx.x * 128;

  __shared__ unsigned short sA[4][128 * 32];
  __shared__ unsigned short sB[4][128 * 32];

  int tid = threadIdx.x, w = tid >> 6, lane = tid & 63;
  int l15 = lane & 15, lhi = lane >> 4;

  int srow = w * 16 + (lane >> 2);
  int schunk = ((lane & 3) ^ ((lane >> 2) & 3)) * 8;
  const unsigned short *aSrc0, *aSrc1, *bSrc0, *bSrc1;
  {
    int mr0 = m0 + srow, mr1 = m0 + 64 + srow;
    int ar0, ar1;
    if (GATHER == 0) { ar0 = mr0; ar1 = mr1; }
    else {
      int c0i = mr0 < count ? mr0 : count - 1;
      int c1i = mr1 < count ? mr1 : count - 1;
      int p0 = lst[c0i], p1 = lst[c1i];
      ar0 = (GATHER == 1) ? (p0 >> 1) : p0;
      ar1 = (GATHER == 1) ? (p1 >> 1) : p1;
    }
    aSrc0 = A + (size_t)ar0 * lda + schunk;
    aSrc1 = A + (size_t)ar1 * lda + schunk;
    bSrc0 = B + (size_t)(n0 + srow) * ldb + schunk;
    bSrc1 = B + (size_t)(n0 + 64 + srow) * ldb + schunk;
  }
  unsigned ldst = (unsigned)(w * 16) * 32;  // element offset of wave's chunk

#define STAGE(buf, k0)                                   \
  do {                                                   \
    gload16(aSrc0 + (k0), &sA[buf][ldst]);               \
    gload16(aSrc1 + (k0), &sA[buf][ldst + 64 * 32]);     \
    gload16(bSrc0 + (k0), &sB[buf][ldst]);               \
    gload16(bSrc1 + (k0), &sB[buf][ldst + 64 * 32]);     \
  } while (0)

  f32x4 acc[4][4] = {};
  int wm = w >> 1, wn = w & 1;
  int aoff[4], boff[4];
#pragma unroll
  for (int t = 0; t < 4; ++t) {
    int row = wm * 64 + t * 16 + l15;
    aoff[t] = row * 32 + ((lhi ^ (row & 3)) * 8);
    int col = wn * 64 + t * 16 + l15;
    boff[t] = col * 32 + ((lhi ^ (col & 3)) * 8);
  }

  int nsteps = K / 32;
  // prologue: 3 tiles in flight (12 loads/wave outstanding)
  STAGE(0, 0);
  if (nsteps > 1) STAGE(1, 32);
  if (nsteps > 2) STAGE(2, 64);

  for (int t = 0; t < nsteps; ++t) {
    int rem = nsteps - 1 - t;
    // own tile-t loads are the oldest 4 in FIFO; after this, <=2 tiles remain in flight
    if (rem >= 2)      asm volatile("s_waitcnt vmcnt(8)" ::: "memory");
    else if (rem == 1) asm volatile("s_waitcnt vmcnt(4)" ::: "memory");
    else               asm volatile("s_waitcnt vmcnt(0)" ::: "memory");
    __builtin_amdgcn_s_barrier();          // all waves' tile-t data now in LDS
    __builtin_amdgcn_sched_barrier(0);
    if (t + 3 < nsteps) STAGE((t + 3) & 3, (t + 3) * 32);  // refills buf[(t-1)&3]
    const unsigned short* pa = sA[t & 3];
    const unsigned short* pb = sB[t & 3];
    short8 af[4], bfr[4];
#pragma unroll
    for (int q = 0; q < 4; ++q) {
      af[q] = *(const short8*)&pa[aoff[q]];
      bfr[q] = *(const short8*)&pb[boff[q]];
    }
#pragma unroll
    for (int mi = 0; mi < 4; ++mi)
#pragma unroll
      for (int ni = 0; ni < 4; ++ni)
        acc[mi][ni] =
            __builtin_amdgcn_mfma_f32_16x16x32_bf16(af[mi], bfr[ni], acc[mi][ni], 0, 0, 0);
  }
#undef STAGE

#pragma unroll
  for (int mi = 0; mi < 4; ++mi) {
#pragma unroll
    for (int r = 0; r < 4; ++r) {
      int mr = m0 + wm * 64 + mi * 16 + lhi * 4 + r;
      if (GATHER != 0 && mr >= count) continue;
      size_t crow = (GATHER != 0) ? (size_t)lst[mr] : (size_t)mr;
#pragma unroll
      for (int ni = 0; ni < 4; ++ni) {
        int n = n0 + wn * 64 + ni * 16 + l15;
        float val = acc[mi][ni][r];
        if (EPI == 0)
          ((unsigned short*)Cv)[crow * ldc + n] = f2bf(val);
        else if (EPI == 1)
          ((float*)Cv)[crow * ldc + n] = val + resid[crow * ldc + n];
        else
          ((float*)Cv)[crow * ldc + n] = val;
      }
    }
  }
}

// ---------------------------------------------------------------- RoPE (in-place on fused qkv)
__global__ void __launch_bounds__(256) rope_kernel(unsigned short* __restrict__ qkv) {
  int g = blockIdx.x * 256 + threadIdx.x;
  int i = g & 31;
  int hh = (g >> 5) % (NH + NKV);
  int tok = g / (32 * (NH + NKV));
  if (tok >= NT) return;
  int s = tok & (SEQ - 1);
  float inv = exp2f((float)i * (-13.287712379549449f / 32.0f));
  float ang = (float)s * inv;
  float sn = sinf(ang);
  float c = cosf(ang);
  int col = (hh < NH) ? hh * HD : DIM + (hh - NH) * HD;
  unsigned short* ptr = qkv + (size_t)tok * QW + col;
  float a = bf2f(ptr[i]), b2 = bf2f(ptr[i + 32]);
  ptr[i] = f2bf(a * c - b2 * sn);
  ptr[i + 32] = f2bf(b2 * c + a * sn);
}

// ---------------------------------------------------------------- flash attention
__global__ void __launch_bounds__(64) attn_kernel(const unsigned short* __restrict__ qkv,
                                                  unsigned short* __restrict__ ao) {
  __shared__ unsigned short Ps[16 * 64];
  int bid = blockIdx.x;
  int qt = bid & 63;
  int h = (bid >> 6) & 15;
  int b = bid >> 10;
  int lane = threadIdx.x, l15 = lane & 15, lhi = lane >> 4;
  int q0 = qt * 16, kvh = h >> 1;
  int kcol = DIM + kvh * HD, vcol = DIM + NKV * HD + kvh * HD;

  const unsigned short* qp = qkv + ((size_t)(b * SEQ + q0 + l15)) * QW + h * HD + lhi * 8;
  short8 aq0 = *(const short8*)qp;
  short8 aq1 = *(const short8*)(qp + 32);

  float m[4] = {-1e30f, -1e30f, -1e30f, -1e30f};
  float l[4] = {0.f, 0.f, 0.f, 0.f};
  f32x4 accO[4] = {};

  int nkb = (qt >> 2) + 1;
  for (int kb_ = 0; kb_ < nkb; ++kb_) {
    int kbase = kb_ * 64;
    f32x4 s[4];
#pragma unroll
    for (int ct = 0; ct < 4; ++ct) {
      const unsigned short* kp =
          qkv + ((size_t)(b * SEQ + kbase + ct * 16 + l15)) * QW + kcol + lhi * 8;
      short8 k0v = *(const short8*)kp;
      short8 k1v = *(const short8*)(kp + 32);
      f32x4 a = {};
      a = __builtin_amdgcn_mfma_f32_16x16x32_bf16(aq0, k0v, a, 0, 0, 0);
      a = __builtin_amdgcn_mfma_f32_16x16x32_bf16(aq1, k1v, a, 0, 0, 0);
      int kpos = kbase + ct * 16 + l15;
#pragma unroll
      for (int r = 0; r < 4; ++r) {
        float v = a[r] * 0.125f;
        if (kpos > q0 + lhi * 4 + r) v = -1e30f;
        s[ct][r] = v;
      }
    }
    float nm[4], al[4], rs[4];
#pragma unroll
    for (int r = 0; r < 4; ++r) {
      float mb = fmaxf(fmaxf(s[0][r], s[1][r]), fmaxf(s[2][r], s[3][r]));
      mb = fmaxf(mb, __shfl_xor(mb, 1));
      mb = fmaxf(mb, __shfl_xor(mb, 2));
      mb = fmaxf(mb, __shfl_xor(mb, 4));
      mb = fmaxf(mb, __shfl_xor(mb, 8));
      nm[r] = fmaxf(m[r], mb);
      al[r] = __expf(m[r] - nm[r]);
      m[r] = nm[r];
      rs[r] = 0.f;
    }
#pragma unroll
    for (int ct = 0; ct < 4; ++ct) {
#pragma unroll
      for (int r = 0; r < 4; ++r) {
        float p = __expf(s[ct][r] - nm[r]);
        rs[r] += p;
        int q = lhi * 4 + r;
        Ps[q * 64 + ((ct * 16 + l15) ^ (lhi << 4))] = f2bf(p);
      }
    }
#pragma unroll
    for (int r = 0; r < 4; ++r) {
      rs[r] += __shfl_xor(rs[r], 1);
      rs[r] += __shfl_xor(rs[r], 2);
      rs[r] += __shfl_xor(rs[r], 4);
      rs[r] += __shfl_xor(rs[r], 8);
      l[r] = l[r] * al[r] + rs[r];
    }
#pragma unroll
    for (int dt = 0; dt < 4; ++dt)
#pragma unroll
      for (int r = 0; r < 4; ++r) accO[dt][r] *= al[r];

    int pswz = (l15 >> 2) << 4;
    short8 ap0 = *(const short8*)&Ps[l15 * 64 + ((lhi * 8) ^ pswz)];
    short8 ap1 = *(const short8*)&Ps[l15 * 64 + ((32 + lhi * 8) ^ pswz)];
#pragma unroll
    for (int dt = 0; dt < 4; ++dt) {
#pragma unroll
      for (int ks = 0; ks < 2; ++ks) {
        const unsigned short* vp =
            qkv + ((size_t)(b * SEQ + kbase + ks * 32 + lhi * 8)) * QW + vcol + dt * 16 + l15;
        short8 vf;
#pragma unroll
        for (int j = 0; j < 8; ++j) vf[j] = (short)vp[(size_t)j * QW];
        accO[dt] = __builtin_amdgcn_mfma_f32_16x16x32_bf16(ks ? ap1 : ap0, vf, accO[dt], 0, 0, 0);
      }
    }
  }
  float invl[4];
#pragma unroll
  for (int r = 0; r < 4; ++r) invl[r] = 1.f / l[r];
#pragma unroll
  for (int dt = 0; dt < 4; ++dt)
#pragma unroll
    for (int r = 0; r < 4; ++r)
      ao[((size_t)(b * SEQ + q0 + lhi * 4 + r)) * DIM + h * HD + dt * 16 + l15] =
          f2bf(accO[dt][r] * invl[r]);
}

// ---------------------------------------------------------------- zero counts
__global__ void zero_cnt_kernel(int* __restrict__ cnt) {
  if (threadIdx.x < NE) cnt[threadIdx.x] = 0;
}

// ---------------------------------------------------------------- router (top-2, fp32 + fp64 accum)
__global__ void __launch_bounds__(64) router_kernel(const float* __restrict__ x2,
                                                    const float* __restrict__ ln2w,
                                                    const float* __restrict__ rw,
                                                    float* __restrict__ wts,
                                                    int* __restrict__ cnt,
                                                    int* __restrict__ lists) {
  int t = blockIdx.x, lane = threadIdx.x;
  const float* xr = x2 + (size_t)t * DIM;
  float xs[16];
  double ssq = 0.0;
#pragma unroll
  for (int j = 0; j < 16; ++j) {
    xs[j] = xr[lane + j * 64];
    ssq += (double)xs[j] * xs[j];
  }
  for (int o = 32; o; o >>= 1) ssq += __shfl_xor(ssq, o);
  double r = rsqrt(ssq * (1.0 / DIM) + 1e-6);
  double p[NE] = {};
#pragma unroll
  for (int j = 0; j < 16; ++j) {
    int i = lane + j * 64;
    double hv = (double)xs[j] * r * (double)ln2w[i];
    const float* rwp = rw + (size_t)i * NE;
#pragma unroll
    for (int e = 0; e < NE; ++e) p[e] += hv * (double)rwp[e];
  }
  for (int o = 32; o; o >>= 1) {
#pragma unroll
    for (int e = 0; e < NE; ++e) p[e] += __shfl_xor(p[e], o);
  }
  if (lane == 0) {
    int i1 = 0;
    for (int e = 1; e < NE; ++e)
      if (p[e] > p[i1]) i1 = e;
    int i2 = (i1 == 0) ? 1 : 0;
    for (int e = 0; e < NE; ++e)
      if (e != i1 && p[e] > p[i2]) i2 = e;
    double mx = fmax(p[i1], p[i2]);
    double e1 = exp(p[i1] - mx), e2 = exp(p[i2] - mx);
    double inv = 1.0 / (e1 + e2);
    wts[t * 2] = (float)(e1 * inv);
    wts[t * 2 + 1] = (float)(e2 * inv);
    int pos1 = atomicAdd(&cnt[i1], 1);
    lists[i1 * NT + pos1] = t * 2;
    int pos2 = atomicAdd(&cnt[i2], 1);
    lists[i2 * NT + pos2] = t * 2 + 1;
  }
}

// ---------------------------------------------------------------- SwiGLU elementwise
__global__ void __launch_bounds__(256) swiglu_kernel(const unsigned short* __restrict__ gu,
                                                     const float* __restrict__ wts,
                                                     unsigned short* __restrict__ act) {
  size_t i = ((size_t)blockIdx.x * 256 + threadIdx.x) * 8;
  int pid = (int)(i / MDIM);
  int mcol = (int)(i - (size_t)pid * MDIM);
  float w = wts[pid];
  const unsigned short* row = gu + (size_t)pid * GUW;
  short8 g8 = *(const short8*)(row + mcol);
  short8 u8 = *(const short8*)(row + MDIM + mcol);
  short8 o8;
#pragma unroll
  for (int j = 0; j < 8; ++j) {
    float gv = bf2f((unsigned short)g8[j]);
    float uv = bf2f((unsigned short)u8[j]);
    float sv = gv / (1.f + __expf(-gv));
    o8[j] = (short)f2bf(sv * uv * w);
  }
  *(short8*)(act + i) = o8;
}

// ---------------------------------------------------------------- combine
__global__ void __launch_bounds__(256) combine_kernel(const float* __restrict__ x2,
                                                      const float* __restrict__ part,
                                                      float* __restrict__ out) {
  size_t idx = ((size_t)blockIdx.x * 256 + threadIdx.x) * 4;
  size_t t = idx >> 10;
  size_t d = idx & 1023;
  float4 a = *(const float4*)(x2 + idx);
  float4 b = *(const float4*)(part + (t * 2) * DIM + d);
  float4 c = *(const float4*)(part + (t * 2 + 1) * DIM + d);
  float4 o;
  o.x = a.x + b.x + c.x;
  o.y = a.y + b.y + c.y;
  o.z = a.z + b.z + c.z;
  o.w = a.w + b.w + c.w;
  *(float4*)(out + idx) = o;
}

// ---------------------------------------------------------------- launch
extern "C" void kernel_launch(void* const* d_in, const int* in_sizes, int n_in,
                              void* d_out, int out_size, void* d_ws, size_t ws_size,
                              hipStream_t stream) {
  const float* x   = (const float*)d_in[0];
  const float* ln1 = (const float*)d_in[1];
  const float* ln2 = (const float*)d_in[2];
  const float* wq  = (const float*)d_in[3];
  const float* wk  = (const float*)d_in[4];
  const float* wv  = (const float*)d_in[5];
  const float* wo  = (const float*)d_in[6];
  const float* rw  = (const float*)d_in[7];
  const float* wg  = (const float*)d_in[8];
  const float* wu  = (const float*)d_in[9];
  const float* wd  = (const float*)d_in[10];
  float* out = (float*)d_out;

  char* p = (char*)d_ws;
  auto take = [&](size_t bytes) {
    char* q = p;
    p += (bytes + 255) & ~(size_t)255;
    return q;
  };
  // persistent
  unsigned short* wguT = (unsigned short*)take((size_t)NE * GUW * DIM * 2);   // 117 MB
  unsigned short* wdT  = (unsigned short*)take((size_t)NE * DIM * MDIM * 2);  // 59 MB
  float*          x2   = (float*)take((size_t)NT * DIM * 4);
  unsigned short* h2   = (unsigned short*)take((size_t)NT * DIM * 2);
  float*          part = (float*)take((size_t)2 * NT * DIM * 4);
  unsigned short* act  = (unsigned short*)take((size_t)2 * NT * MDIM * 2);
  float*          wtsb = (float*)take((size_t)2 * NT * 4);
  int*            cntb = (int*)take(NE * 4);
  int*            listsb = (int*)take((size_t)NE * NT * 4);
  // overlay region X: phase A (prep/attn) then phase B (gu)
  char* X = p;
  unsigned short* wqkvT = (unsigned short*)X;                 // [2048][1024]
  unsigned short* woT   = wqkvT + (size_t)QW * DIM;           // [1024][1024]
  unsigned short* h1    = woT + (size_t)DIM * DIM;
  unsigned short* qkv   = h1 + (size_t)NT * DIM;              // [NT][2048]
  unsigned short* aob   = qkv + (size_t)NT * QW;              // [NT][1024]
  unsigned short* gu    = (unsigned short*)X;                 // [2*NT][7168]

  // ---- weight prep: transpose+convert to bf16 [N][K]
  transpose_kernel<<<dim3(16, 16, 1), 256, 0, stream>>>(wq, wqkvT, DIM, DIM, 0, 0);
  transpose_kernel<<<dim3(8, 16, 1), 256, 0, stream>>>(wk, wqkvT + (size_t)DIM * DIM, DIM, 512, 0, 0);
  transpose_kernel<<<dim3(8, 16, 1), 256, 0, stream>>>(wv, wqkvT + (size_t)(DIM + 512) * DIM, DIM, 512, 0, 0);
  transpose_kernel<<<dim3(16, 16, 1), 256, 0, stream>>>(wo, woT, DIM, DIM, 0, 0);
  transpose_kernel<<<dim3(56, 16, NE), 256, 0, stream>>>(
      wg, wguT, DIM, MDIM, (size_t)DIM * MDIM, (size_t)GUW * DIM);
  transpose_kernel<<<dim3(56, 16, NE), 256, 0, stream>>>(
      wu, wguT + (size_t)MDIM * DIM, DIM, MDIM, (size_t)DIM * MDIM, (size_t)GUW * DIM);
  transpose_kernel<<<dim3(16, 56, NE), 256, 0, stream>>>(
      wd, wdT, MDIM, DIM, (size_t)MDIM * DIM, (size_t)DIM * MDIM);

  // ---- attention block
  rmsnorm_kernel<<<NT, 256, 0, stream>>>(x, ln1, h1);
  gemmT_kernel<0, 0><<<dim3(QW / 128, NT / 128, 1), 256, 0, stream>>>(
      h1, DIM, wqkvT, DIM, 0, qkv, QW, nullptr, NT, DIM, nullptr, nullptr);
  rope_kernel<<<(NT * (NH + NKV) * 32) / 256, 256, 0, stream>>>(qkv);
  attn_kernel<<<NT * NH / 16, 64, 0, stream>>>(qkv, aob);
  gemmT_kernel<0, 1><<<dim3(DIM / 128, NT / 128, 1), 256, 0, stream>>>(
      aob, DIM, woT, DIM, 0, x2, DIM, x, NT, DIM, nullptr, nullptr);

  // ---- MoE block
  rmsnorm_kernel<<<NT, 256, 0, stream>>>(x2, ln2, h2);
  zero_cnt_kernel<<<1, 64, 0, stream>>>(cntb);
  router_kernel<<<NT, 64, 0, stream>>>(x2, ln2, rw, wtsb, cntb, listsb);

  gemmT_kernel<1, 0><<<dim3(GUW / 128, 16, NE), 256, 0, stream>>>(
      h2, DIM, wguT, DIM, (size_t)GUW * DIM, gu, GUW, nullptr, 0, DIM, listsb, cntb);
  swiglu_kernel<<<(int)(((size_t)2 * NT * MDIM) / (256 * 8)), 256, 0, stream>>>(
      gu, wtsb, act);
  gemmT_kernel<2, 2><<<dim3(DIM / 128, 16, NE), 256, 0, stream>>>(
      act, MDIM, wdT, MDIM, (size_t)DIM * MDIM, part, DIM, nullptr, 0, MDIM, listsb, cntb);

  combine_kernel<<<(NT * DIM) / 1024, 256, 0, stream>>>(x2, part, out);
}